// Round 7
// baseline (1812.008 us; speedup 1.0000x reference)
//
#include <hip/hip_runtime.h>
#include <cfloat>

#define NB  32
#define ND  256
#define NK  512
#define NHW 4096
#define PXT 32            // pixels per block
#define ZSTR 260          // Zs row stride (floats); 260*4=1040B = 65*16 -> f4-aligned
#define MARGIN 1.3e-4f    // >= 2 ulps for |X|<1024; fast-vs-np diff <= ~1 ulp (validated R6)
#define QCAP 16

// C declared int64 in the reference; detect storage width on device.
__device__ __forceinline__ int loadC(const int* __restrict__ C, int b) {
  int orodd = 0;
#pragma unroll
  for (int i = 1; i < 32; i += 2) orodd |= C[i];
  return (orodd == 0) ? C[2 * b] : C[b];
}

// np.sum pairwise block (n=128) on fl(z*z) — verbatim from passing R5/R6.
__device__ __forceinline__ float pwsq128(const float* __restrict__ a) {
  float r[8];
#pragma unroll
  for (int j = 0; j < 8; ++j) r[j] = __fmul_rn(a[j], a[j]);
  for (int i = 8; i < 128; i += 8)
#pragma unroll
    for (int j = 0; j < 8; ++j)
      r[j] = __fadd_rn(r[j], __fmul_rn(a[i + j], a[i + j]));
  return __fadd_rn(
      __fadd_rn(__fadd_rn(r[0], r[1]), __fadd_rn(r[2], r[3])),
      __fadd_rn(__fadd_rn(r[4], r[5]), __fadd_rn(r[6], r[7])));
}

// Exact np-replica score for one (pixel,code) — verbatim op order from R5/R6.
__device__ float np_score(const float* __restrict__ zrow,
                          const float* __restrict__ er, float S) {
  float P0 = 0.f, P1 = 0.f, P2 = 0.f, P3 = 0.f;
  for (int ch = 0; ch < 16; ++ch) {
    const float* eb = er + ch * 16;
    float4 e0 = *(const float4*)(eb + 0);
    float4 e1 = *(const float4*)(eb + 4);
    float4 e2 = *(const float4*)(eb + 8);
    float4 e3 = *(const float4*)(eb + 12);
    const float* zb = zrow + ch * 16;
    float4 z0 = *(const float4*)(zb + 0);
    float4 z1 = *(const float4*)(zb + 4);
    float4 z2 = *(const float4*)(zb + 8);
    float4 z3 = *(const float4*)(zb + 12);
    P0 = __fadd_rn(P0, __fmul_rn(z3.x, e3.x));
    P0 = __fadd_rn(P0, __fmul_rn(z2.x, e2.x));
    P0 = __fadd_rn(P0, __fmul_rn(z1.x, e1.x));
    P0 = __fadd_rn(P0, __fmul_rn(z0.x, e0.x));
    P1 = __fadd_rn(P1, __fmul_rn(z3.y, e3.y));
    P1 = __fadd_rn(P1, __fmul_rn(z2.y, e2.y));
    P1 = __fadd_rn(P1, __fmul_rn(z1.y, e1.y));
    P1 = __fadd_rn(P1, __fmul_rn(z0.y, e0.y));
    P2 = __fadd_rn(P2, __fmul_rn(z3.z, e3.z));
    P2 = __fadd_rn(P2, __fmul_rn(z2.z, e2.z));
    P2 = __fadd_rn(P2, __fmul_rn(z1.z, e1.z));
    P2 = __fadd_rn(P2, __fmul_rn(z0.z, e0.z));
    P3 = __fadd_rn(P3, __fmul_rn(z3.w, e3.w));
    P3 = __fadd_rn(P3, __fmul_rn(z2.w, e2.w));
    P3 = __fadd_rn(P3, __fmul_rn(z1.w, e1.w));
    P3 = __fadd_rn(P3, __fmul_rn(z0.w, e0.w));
  }
  float G = __fadd_rn(__fadd_rn(P0, P1), __fadd_rn(P2, P3));
  return __fadd_rn(S, __fmul_rn(-2.0f, G));
}

__global__ __launch_bounds__(256, 2) void k_fused3(
    const float* __restrict__ z, const int* __restrict__ Cc,
    const float* __restrict__ w, float* __restrict__ out) {
  __shared__ float Zs[PXT][ZSTR];   // 33.3 KB
  __shared__ float Ssh[PXT];
  __shared__ int   qcnt[PXT];
  __shared__ int   qk[PXT][QCAP];   // 2 KB
  __shared__ int   KB[PXT];

  int blk = blockIdx.x;             // 4096 = 32 b * 128 tiles
  int b   = blk >> 7;
  int n0  = (blk & 127) * PXT;
  int c   = loadC(Cc, b);
  int t   = threadIdx.x;
  int kg  = t & 63;                 // lane: k-group (8 codes)
  int pg  = t >> 6;                 // wave: px-group (8 pixels)

  // ---- phase 0: stage z tile [32 px][256 d] ----
  {
    int px = t & 31, dg = t >> 5;
    const float* zp = z + (size_t)b * ND * NHW + n0 + px;
#pragma unroll
    for (int j = 0; j < 32; ++j) {
      int d = dg * 32 + j;
      Zs[px][d] = zp[(size_t)d * NHW];
    }
  }
  if (t < PXT) qcnt[t] = 0;
  __syncthreads();

  // ---- phase 0b: S[px] np pairwise replica ----
  if (t < PXT)
    Ssh[t] = __fadd_rn(pwsq128(&Zs[t][0]), pwsq128(&Zs[t][128]));
  __syncthreads();

  // ---- phase 1: fast FMA scores, 8px x 8k register tile ----
  float acc[8][8];
#pragma unroll
  for (int i = 0; i < 8; ++i)
#pragma unroll
    for (int j = 0; j < 8; ++j) acc[i][j] = 0.f;

  const float* ep = w + ((size_t)c * NK + (size_t)kg * 8) * ND;

  for (int s = 0; s < 64; ++s) {
    float4 ev[8], zv[8];
#pragma unroll
    for (int j = 0; j < 8; ++j)
      ev[j] = *(const float4*)(ep + j * ND + s * 4);       // global/L2/L1
#pragma unroll
    for (int i = 0; i < 8; ++i)
      zv[i] = *(const float4*)&Zs[pg * 8 + i][s * 4];      // LDS broadcast
#pragma unroll
    for (int i = 0; i < 8; ++i)
#pragma unroll
      for (int j = 0; j < 8; ++j) {
        acc[i][j] = fmaf(zv[i].x, ev[j].x, acc[i][j]);
        acc[i][j] = fmaf(zv[i].y, ev[j].y, acc[i][j]);
        acc[i][j] = fmaf(zv[i].z, ev[j].z, acc[i][j]);
        acc[i][j] = fmaf(zv[i].w, ev[j].w, acc[i][j]);
      }
  }

  // ---- phase 1b: X = fl(S + fl(-2G)), per-px wave min -> threshold ----
  float thr[8];
#pragma unroll
  for (int i = 0; i < 8; ++i) {
    float S = Ssh[pg * 8 + i];
    float m = FLT_MAX;
#pragma unroll
    for (int j = 0; j < 8; ++j) {
      float X = __fadd_rn(S, __fmul_rn(-2.0f, acc[i][j]));
      acc[i][j] = X;
      m = fminf(m, X);
    }
#pragma unroll
    for (int off = 1; off < 64; off <<= 1)
      m = fminf(m, __shfl_xor(m, off));
    thr[i] = m + MARGIN;
  }

  // ---- phase 1c: enqueue candidates (expected ~1.3 per pixel) ----
#pragma unroll
  for (int i = 0; i < 8; ++i) {
    int px = pg * 8 + i;
#pragma unroll
    for (int j = 0; j < 8; ++j) {
      if (acc[i][j] <= thr[i]) {
        int slot = atomicAdd(&qcnt[px], 1);
        if (slot < QCAP) qk[px][slot] = kg * 8 + j;
      }
    }
  }
  __syncthreads();

  // ---- phase 2: wave-parallel exact np re-score; lane = (px, slot) ----
  {
    int lane = kg;
    int px   = pg * 8 + (lane >> 3);
    int cnt  = qcnt[px]; cnt = (cnt < QCAP) ? cnt : QCAP;
    float S  = Ssh[px];
    float bv = FLT_MAX; int bk = 0x7fffffff;
#pragma unroll
    for (int m = 0; m < 2; ++m) {
      int slot = (lane & 7) + 8 * m;
      bool act = slot < cnt;
      if (__any(act)) {
        if (act) {
          int k = qk[px][slot];
          float v = np_score(&Zs[px][0], w + ((size_t)c * NK + k) * ND, S);
          if (v < bv || (v == bv && k < bk)) { bv = v; bk = k; }
        }
      }
    }
#pragma unroll
    for (int off = 1; off < 8; off <<= 1) {
      float ov = __shfl_xor(bv, off);
      int   ok = __shfl_xor(bk, off);
      if (ov < bv || (ov == bv && ok < bk)) { bv = ov; bk = ok; }
    }
    if ((lane & 7) == 0) KB[px] = bk;
  }
  __syncthreads();

  // ---- phase 3: gather + transpose-write both outputs ----
  {
    int px = t & 31, dg = t >> 5;
    int kidx = KB[px];
    const float* er = w + ((size_t)c * NK + kidx) * ND;
    const size_t OUT2 = (size_t)NB * ND * NHW;
    size_t base = (size_t)b * ND * NHW + n0 + px;
#pragma unroll
    for (int j = 0; j < 32; ++j) {
      int d = dg * 32 + j;
      float q  = er[d];
      float zv = Zs[px][d];
      out[base + (size_t)d * NHW]        = __fadd_rn(zv, __fsub_rn(q, zv));
      out[base + (size_t)d * NHW + OUT2] = q;
    }
  }
}

extern "C" void kernel_launch(void* const* d_in, const int* in_sizes, int n_in,
                              void* d_out, int out_size, void* d_ws, size_t ws_size,
                              hipStream_t stream) {
  const float* z = (const float*)d_in[0];
  const int*   C = (const int*)d_in[1];
  const float* w = (const float*)d_in[2];
  float* out = (float*)d_out;
  k_fused3<<<NB * (NHW / PXT), 256, 0, stream>>>(z, C, w, out);
}

// Round 8
// 666.502 us; speedup vs baseline: 2.7187x; 2.7187x over previous
//
#include <hip/hip_runtime.h>
#include <cfloat>

#define NB  32
#define ND  256
#define NK  512
#define NHW 4096
#define PXT 32            // pixels per block
#define ZSTR 260          // Zs row stride (floats); 1040B = 65*16 -> f4-aligned, odd*16
#define MARGIN 1.3e-4f    // validated R6/R7: fast-FMA vs np diff <= ~1 ulp @ |X|~256
#define QCAP 16

// C declared int64 in the reference; detect storage width on device.
__device__ __forceinline__ int loadC(const int* __restrict__ C, int b) {
  int orodd = 0;
#pragma unroll
  for (int i = 1; i < 32; i += 2) orodd |= C[i];
  return (orodd == 0) ? C[2 * b] : C[b];
}

// np.sum pairwise block (n=128) on fl(z*z) — verbatim from passing R5/R6/R7.
__device__ __forceinline__ float pwsq128(const float* __restrict__ a) {
  float r[8];
#pragma unroll
  for (int j = 0; j < 8; ++j) r[j] = __fmul_rn(a[j], a[j]);
  for (int i = 8; i < 128; i += 8)
#pragma unroll
    for (int j = 0; j < 8; ++j)
      r[j] = __fadd_rn(r[j], __fmul_rn(a[i + j], a[i + j]));
  return __fadd_rn(
      __fadd_rn(__fadd_rn(r[0], r[1]), __fadd_rn(r[2], r[3])),
      __fadd_rn(__fadd_rn(r[4], r[5]), __fadd_rn(r[6], r[7])));
}

// Exact np-replica score for one (pixel,code) — verbatim op order from R5/R6/R7.
__device__ float np_score(const float* __restrict__ zrow,
                          const float* __restrict__ er, float S) {
  float P0 = 0.f, P1 = 0.f, P2 = 0.f, P3 = 0.f;
  for (int ch = 0; ch < 16; ++ch) {
    const float* eb = er + ch * 16;
    float4 e0 = *(const float4*)(eb + 0);
    float4 e1 = *(const float4*)(eb + 4);
    float4 e2 = *(const float4*)(eb + 8);
    float4 e3 = *(const float4*)(eb + 12);
    const float* zb = zrow + ch * 16;
    float4 z0 = *(const float4*)(zb + 0);
    float4 z1 = *(const float4*)(zb + 4);
    float4 z2 = *(const float4*)(zb + 8);
    float4 z3 = *(const float4*)(zb + 12);
    P0 = __fadd_rn(P0, __fmul_rn(z3.x, e3.x));
    P0 = __fadd_rn(P0, __fmul_rn(z2.x, e2.x));
    P0 = __fadd_rn(P0, __fmul_rn(z1.x, e1.x));
    P0 = __fadd_rn(P0, __fmul_rn(z0.x, e0.x));
    P1 = __fadd_rn(P1, __fmul_rn(z3.y, e3.y));
    P1 = __fadd_rn(P1, __fmul_rn(z2.y, e2.y));
    P1 = __fadd_rn(P1, __fmul_rn(z1.y, e1.y));
    P1 = __fadd_rn(P1, __fmul_rn(z0.y, e0.y));
    P2 = __fadd_rn(P2, __fmul_rn(z3.z, e3.z));
    P2 = __fadd_rn(P2, __fmul_rn(z2.z, e2.z));
    P2 = __fadd_rn(P2, __fmul_rn(z1.z, e1.z));
    P2 = __fadd_rn(P2, __fmul_rn(z0.z, e0.z));
    P3 = __fadd_rn(P3, __fmul_rn(z3.w, e3.w));
    P3 = __fadd_rn(P3, __fmul_rn(z2.w, e2.w));
    P3 = __fadd_rn(P3, __fmul_rn(z1.w, e1.w));
    P3 = __fadd_rn(P3, __fmul_rn(z0.w, e0.w));
  }
  float G = __fadd_rn(__fadd_rn(P0, P1), __fadd_rn(P2, P3));
  return __fadd_rn(S, __fmul_rn(-2.0f, G));
}

__global__ __launch_bounds__(256, 2) void k_fused4(
    const float* __restrict__ z, const int* __restrict__ Cc,
    const float* __restrict__ w, float* __restrict__ out) {
  __shared__ __align__(16) float Zs[PXT][ZSTR];  // 33.3 KB
  __shared__ __align__(16) float Es[NK][8];      // 16 KB: d-chunk slice of all codes
  __shared__ float Ssh[PXT];
  __shared__ int   qcnt[PXT];
  __shared__ int   qk[PXT][QCAP];
  __shared__ int   KB[PXT];

  int blk  = blockIdx.x;            // 4096 = 32 b * 128 tiles
  int b    = blk >> 7;
  int n0   = (blk & 127) * PXT;
  int c    = loadC(Cc, b);
  int t    = threadIdx.x;
  int lane = t & 63;
  int wv   = t >> 6;                // wave owns px-group: px = wv*8 + i

  // ---- phase 0: stage z tile [32 px][256 d]; init queue ----
  {
    int px = t & 31, dg = t >> 5;
    const float* zp = z + (size_t)b * ND * NHW + n0 + px;
#pragma unroll
    for (int j = 0; j < 32; ++j) {
      int d = dg * 32 + j;
      Zs[px][d] = zp[(size_t)d * NHW];
    }
  }
  if (t < PXT) qcnt[t] = 0;
  __syncthreads();

  // ---- phase 0b: S[px] np pairwise replica ----
  if (t < PXT)
    Ssh[t] = __fadd_rn(pwsq128(&Zs[t][0]), pwsq128(&Zs[t][128]));

  // ---- phase 1: fast FMA GEMM, 8px x 8k per thread, E staged in LDS ----
  float acc[8][8];
#pragma unroll
  for (int i = 0; i < 8; ++i)
#pragma unroll
    for (int j = 0; j < 8; ++j) acc[i][j] = 0.f;

  const float* wb = w + (size_t)c * NK * ND;

  for (int dc = 0; dc < 32; ++dc) {           // 32 chunks of 8 dims
    __syncthreads();                          // Es of prev chunk fully consumed
    // stage Es[512][8]: 2 passes, one row (8 floats, 32B) per thread
#pragma unroll
    for (int pass = 0; pass < 2; ++pass) {
      int r = pass * 256 + t;
      const float* src = wb + (size_t)r * ND + dc * 8;
      float4 a0 = *(const float4*)(src + 0);
      float4 a1 = *(const float4*)(src + 4);
      *(float4*)&Es[r][0] = a0;
      *(float4*)&Es[r][4] = a1;
    }
    __syncthreads();
#pragma unroll
    for (int sub = 0; sub < 2; ++sub) {       // two d4 sub-steps
      int d0 = dc * 8 + sub * 4;
      float4 zv[8], ev[8];
#pragma unroll
      for (int i = 0; i < 8; ++i)
        zv[i] = *(const float4*)&Zs[wv * 8 + i][d0];       // broadcast (free)
#pragma unroll
      for (int j = 0; j < 8; ++j)
        ev[j] = *(const float4*)&Es[lane + 64 * j][sub * 4]; // 2-way (free)
#pragma unroll
      for (int i = 0; i < 8; ++i)
#pragma unroll
        for (int j = 0; j < 8; ++j) {
          acc[i][j] = fmaf(zv[i].x, ev[j].x, acc[i][j]);
          acc[i][j] = fmaf(zv[i].y, ev[j].y, acc[i][j]);
          acc[i][j] = fmaf(zv[i].z, ev[j].z, acc[i][j]);
          acc[i][j] = fmaf(zv[i].w, ev[j].w, acc[i][j]);
        }
    }
  }

  // ---- phase 1b: X = fl(S + fl(-2G)); per-px min over all 512 k (one wave) ----
  float thr[8];
#pragma unroll
  for (int i = 0; i < 8; ++i) {
    float S = Ssh[wv * 8 + i];
    float m = FLT_MAX;
#pragma unroll
    for (int j = 0; j < 8; ++j) {
      float X = __fadd_rn(S, __fmul_rn(-2.0f, acc[i][j]));
      acc[i][j] = X;
      m = fminf(m, X);
    }
#pragma unroll
    for (int off = 1; off < 64; off <<= 1)
      m = fminf(m, __shfl_xor(m, off));
    thr[i] = m + MARGIN;
  }

  // ---- phase 1c: enqueue candidates (lane owns k = lane + 64*j) ----
#pragma unroll
  for (int i = 0; i < 8; ++i) {
    int px = wv * 8 + i;
#pragma unroll
    for (int j = 0; j < 8; ++j) {
      if (acc[i][j] <= thr[i]) {
        int slot = atomicAdd(&qcnt[px], 1);
        if (slot < QCAP) qk[px][slot] = lane + 64 * j;
      }
    }
  }
  __syncthreads();

  // ---- phase 2: wave-parallel exact np re-score; lane = (px, slot) ----
  {
    int px  = wv * 8 + (lane >> 3);
    int cnt = qcnt[px]; cnt = (cnt < QCAP) ? cnt : QCAP;
    float S = Ssh[px];
    float bv = FLT_MAX; int bk = 0x7fffffff;
#pragma unroll
    for (int m = 0; m < 2; ++m) {
      int slot = (lane & 7) + 8 * m;
      bool act = slot < cnt;
      if (__any(act)) {
        if (act) {
          int k = qk[px][slot];
          float v = np_score(&Zs[px][0], w + ((size_t)c * NK + k) * ND, S);
          if (v < bv || (v == bv && k < bk)) { bv = v; bk = k; }
        }
      }
    }
#pragma unroll
    for (int off = 1; off < 8; off <<= 1) {
      float ov = __shfl_xor(bv, off);
      int   ok = __shfl_xor(bk, off);
      if (ov < bv || (ov == bv && ok < bk)) { bv = ov; bk = ok; }
    }
    if ((lane & 7) == 0) KB[px] = bk;
  }
  __syncthreads();

  // ---- phase 3: gather + transpose-write both outputs (verbatim R5/R7) ----
  {
    int px = t & 31, dg = t >> 5;
    int kidx = KB[px];
    const float* er = w + ((size_t)c * NK + kidx) * ND;
    const size_t OUT2 = (size_t)NB * ND * NHW;
    size_t base = (size_t)b * ND * NHW + n0 + px;
#pragma unroll
    for (int j = 0; j < 32; ++j) {
      int d = dg * 32 + j;
      float q  = er[d];
      float zv = Zs[px][d];
      out[base + (size_t)d * NHW]        = __fadd_rn(zv, __fsub_rn(q, zv));
      out[base + (size_t)d * NHW + OUT2] = q;
    }
  }
}

extern "C" void kernel_launch(void* const* d_in, const int* in_sizes, int n_in,
                              void* d_out, int out_size, void* d_ws, size_t ws_size,
                              hipStream_t stream) {
  const float* z = (const float*)d_in[0];
  const int*   C = (const int*)d_in[1];
  const float* w = (const float*)d_in[2];
  float* out = (float*)d_out;
  k_fused4<<<NB * (NHW / PXT), 256, 0, stream>>>(z, C, w, out);
}

// Round 9
// 316.823 us; speedup vs baseline: 5.7193x; 2.1037x over previous
//
#include <hip/hip_runtime.h>
#include <cfloat>

#define NB    32
#define ND    256
#define NK    512
#define NCOND 16
#define NHW   4096
#define PXT   64
#define ZSTR  260          // floats; 1040B rows, float4-aligned
#define ESTR  40           // ushorts; 80B = 5 granules -> conflict-free b128
#define MARGIN 1.3e-4f     // validated R6-R8; MFMA-fast vs np diff <= ~3.4e-5
#define QCAP  16

typedef __attribute__((ext_vector_type(8))) short bf16x8;   // guide SS3 frag_ab
typedef __attribute__((ext_vector_type(4))) float f32x4;    // guide SS3 frag_cd

// C declared int64 in the reference; detect storage width on device.
__device__ __forceinline__ int loadC(const int* __restrict__ C, int b) {
  int orodd = 0;
#pragma unroll
  for (int i = 1; i < 32; i += 2) orodd |= C[i];
  return (orodd == 0) ? C[2 * b] : C[b];
}

// np.sum pairwise block (n=128) on fl(z*z) — verbatim from passing R5-R8.
__device__ __forceinline__ float pwsq128(const float* __restrict__ a) {
  float r[8];
#pragma unroll
  for (int j = 0; j < 8; ++j) r[j] = __fmul_rn(a[j], a[j]);
  for (int i = 8; i < 128; i += 8)
#pragma unroll
    for (int j = 0; j < 8; ++j)
      r[j] = __fadd_rn(r[j], __fmul_rn(a[i + j], a[i + j]));
  return __fadd_rn(
      __fadd_rn(__fadd_rn(r[0], r[1]), __fadd_rn(r[2], r[3])),
      __fadd_rn(__fadd_rn(r[4], r[5]), __fadd_rn(r[6], r[7])));
}

// Exact np-replica score for one (pixel,code) — verbatim op order from R5-R8.
__device__ float np_score(const float* __restrict__ zrow,
                          const float* __restrict__ er, float S) {
  float P0 = 0.f, P1 = 0.f, P2 = 0.f, P3 = 0.f;
  for (int ch = 0; ch < 16; ++ch) {
    const float* eb = er + ch * 16;
    float4 e0 = *(const float4*)(eb + 0);
    float4 e1 = *(const float4*)(eb + 4);
    float4 e2 = *(const float4*)(eb + 8);
    float4 e3 = *(const float4*)(eb + 12);
    const float* zb = zrow + ch * 16;
    float4 z0 = *(const float4*)(zb + 0);
    float4 z1 = *(const float4*)(zb + 4);
    float4 z2 = *(const float4*)(zb + 8);
    float4 z3 = *(const float4*)(zb + 12);
    P0 = __fadd_rn(P0, __fmul_rn(z3.x, e3.x));
    P0 = __fadd_rn(P0, __fmul_rn(z2.x, e2.x));
    P0 = __fadd_rn(P0, __fmul_rn(z1.x, e1.x));
    P0 = __fadd_rn(P0, __fmul_rn(z0.x, e0.x));
    P1 = __fadd_rn(P1, __fmul_rn(z3.y, e3.y));
    P1 = __fadd_rn(P1, __fmul_rn(z2.y, e2.y));
    P1 = __fadd_rn(P1, __fmul_rn(z1.y, e1.y));
    P1 = __fadd_rn(P1, __fmul_rn(z0.y, e0.y));
    P2 = __fadd_rn(P2, __fmul_rn(z3.z, e3.z));
    P2 = __fadd_rn(P2, __fmul_rn(z2.z, e2.z));
    P2 = __fadd_rn(P2, __fmul_rn(z1.z, e1.z));
    P2 = __fadd_rn(P2, __fmul_rn(z0.z, e0.z));
    P3 = __fadd_rn(P3, __fmul_rn(z3.w, e3.w));
    P3 = __fadd_rn(P3, __fmul_rn(z2.w, e2.w));
    P3 = __fadd_rn(P3, __fmul_rn(z1.w, e1.w));
    P3 = __fadd_rn(P3, __fmul_rn(z0.w, e0.w));
  }
  float G = __fadd_rn(__fadd_rn(P0, P1), __fadd_rn(P2, P3));
  return __fadd_rn(S, __fmul_rn(-2.0f, G));
}

// round-to-nearest-even fp32 -> bf16 (bit trick, finite inputs)
__device__ __forceinline__ unsigned short rne_bf16(float x) {
  unsigned u = __float_as_uint(x);
  u += 0x7fffu + ((u >> 16) & 1u);
  return (unsigned short)(u >> 16);
}

// pre-kernel: split codebook into bf16 hi/lo (RNE): w = hi + lo + O(2^-17)
__global__ __launch_bounds__(256) void k_split(
    const float* __restrict__ w, unsigned short* __restrict__ whi,
    unsigned short* __restrict__ wlo) {
  int i = (blockIdx.x * 256 + threadIdx.x) * 4;
  float4 v = *(const float4*)&w[i];
  ushort4 h, l;
  float hf;
  h.x = rne_bf16(v.x); hf = __uint_as_float((unsigned)h.x << 16); l.x = rne_bf16(v.x - hf);
  h.y = rne_bf16(v.y); hf = __uint_as_float((unsigned)h.y << 16); l.y = rne_bf16(v.y - hf);
  h.z = rne_bf16(v.z); hf = __uint_as_float((unsigned)h.z << 16); l.z = rne_bf16(v.z - hf);
  h.w = rne_bf16(v.w); hf = __uint_as_float((unsigned)h.w << 16); l.w = rne_bf16(v.w - hf);
  *(ushort4*)&whi[i] = h;
  *(ushort4*)&wlo[i] = l;
}

template <int PRE>
__global__ __launch_bounds__(512, 2) void k_mfma(
    const float* __restrict__ z, const int* __restrict__ Cc,
    const float* __restrict__ w,
    const unsigned short* __restrict__ whi,
    const unsigned short* __restrict__ wlo,
    float* __restrict__ out) {
  __shared__ __align__(16) float Zs[PXT][ZSTR];            // 66.6 KB
  __shared__ __align__(16) unsigned short EsH[NK][ESTR];   // 40 KB
  __shared__ __align__(16) unsigned short EsL[NK][ESTR];   // 40 KB
  __shared__ float Ssh[PXT];
  __shared__ float Wmin[8][16];
  __shared__ float Thr[PXT];
  __shared__ int   qcnt[PXT], KB[PXT];
  __shared__ int   qk[PXT][QCAP];

  int blk  = blockIdx.x;          // 2048 = 32 b * 32 tiles... (NHW/64=64) -> 32*64
  int b    = blk >> 6;
  int n0   = (blk & 63) * PXT;
  int c    = loadC(Cc, b);
  int t    = threadIdx.x;         // 0..511
  int lane = t & 63;
  int wv   = t >> 6;              // 0..7
  int mt   = wv >> 1;             // m-tile: px block mt*16
  int nh   = wv & 1;              // n-half: codes nh*256 ..

  // ---- phase 0: stage z tile [64 px][256 d] (coalesced 256B rows) ----
  {
    int px = t & 63, dg = t >> 6;
    const float* zp = z + (size_t)b * ND * NHW + n0 + px;
#pragma unroll
    for (int j = 0; j < 32; ++j) {
      int d = dg * 32 + j;
      Zs[px][d] = zp[(size_t)d * NHW];
    }
  }
  if (t < PXT) qcnt[t] = 0;
  __syncthreads();

  // ---- S[px]: np pairwise replica ----
  if (t < PXT)
    Ssh[t] = __fadd_rn(pwsq128(&Zs[t][0]), pwsq128(&Zs[t][128]));

  // ---- A-fragments (z hi/lo) for all 8 k-steps; row=lane&15, k=(lane>>4)*8+j ----
  int arow = mt * 16 + (lane & 15);
  int koff = (lane >> 4) * 8;
  bf16x8 afh[8], afl[8];
#pragma unroll
  for (int ks = 0; ks < 8; ++ks) {
    const float* zr = &Zs[arow][ks * 32 + koff];
    float4 za = *(const float4*)(zr);
    float4 zb = *(const float4*)(zr + 4);
    float xs[8] = {za.x, za.y, za.z, za.w, zb.x, zb.y, zb.z, zb.w};
    bf16x8 h, l;
#pragma unroll
    for (int j = 0; j < 8; ++j) {
      unsigned short hb = rne_bf16(xs[j]);
      float hf = __uint_as_float((unsigned)hb << 16);
      h[j] = (short)hb;
      l[j] = (short)rne_bf16(xs[j] - hf);
    }
    afh[ks] = h; afl[ks] = l;
  }

  // ---- staging prefetch (T14): thread t owns codebook row t ----
  bf16x8 ph[4], pl[4];   // PRE
  float4 pf[8];          // !PRE
  size_t wrow = ((size_t)c * NK + t) * ND;

  auto issue = [&](int ks) {
    if (PRE) {
      const unsigned short* hr = whi + wrow + ks * 32;
      const unsigned short* lr = wlo + wrow + ks * 32;
#pragma unroll
      for (int j = 0; j < 4; ++j) {
        ph[j] = *(const bf16x8*)(hr + j * 8);
        pl[j] = *(const bf16x8*)(lr + j * 8);
      }
    } else {
      const float* fr = w + wrow + ks * 32;
#pragma unroll
      for (int j = 0; j < 8; ++j) pf[j] = *(const float4*)(fr + j * 4);
    }
  };
  issue(0);

  f32x4 acc[16];
#pragma unroll
  for (int nt = 0; nt < 16; ++nt) acc[nt] = (f32x4){0.f, 0.f, 0.f, 0.f};

  int cbase = nh * 256 + (lane & 15);

#pragma unroll
  for (int ks = 0; ks < 8; ++ks) {
    __syncthreads();              // Es of previous step fully consumed
    if (PRE) {
#pragma unroll
      for (int j = 0; j < 4; ++j) {
        *(bf16x8*)&EsH[t][j * 8] = ph[j];
        *(bf16x8*)&EsL[t][j * 8] = pl[j];
      }
    } else {
#pragma unroll
      for (int j = 0; j < 4; ++j) {
        float xs[8] = {pf[2 * j].x, pf[2 * j].y, pf[2 * j].z, pf[2 * j].w,
                       pf[2 * j + 1].x, pf[2 * j + 1].y, pf[2 * j + 1].z, pf[2 * j + 1].w};
        bf16x8 h, l;
#pragma unroll
        for (int q = 0; q < 8; ++q) {
          unsigned short hb = rne_bf16(xs[q]);
          float hf = __uint_as_float((unsigned)hb << 16);
          h[q] = (short)hb;
          l[q] = (short)rne_bf16(xs[q] - hf);
        }
        *(bf16x8*)&EsH[t][j * 8] = h;
        *(bf16x8*)&EsL[t][j * 8] = l;
      }
    }
    if (ks < 7) issue(ks + 1);    // prefetch next chunk; latency hides under MFMA
    __syncthreads();              // Es ready
    bf16x8 ah = afh[ks], al = afl[ks];
#pragma unroll
    for (int nt = 0; nt < 16; ++nt) {
      const bf16x8 bh = *(const bf16x8*)&EsH[cbase + nt * 16][koff];
      const bf16x8 bl = *(const bf16x8*)&EsL[cbase + nt * 16][koff];
      acc[nt] = __builtin_amdgcn_mfma_f32_16x16x32_bf16(ah, bh, acc[nt], 0, 0, 0);
      acc[nt] = __builtin_amdgcn_mfma_f32_16x16x32_bf16(al, bh, acc[nt], 0, 0, 0);
      acc[nt] = __builtin_amdgcn_mfma_f32_16x16x32_bf16(ah, bl, acc[nt], 0, 0, 0);
    }
  }

  // ---- X = fl(S + fl(-2G)); per-px min (D: row=(lane>>4)*4+r, col=lane&15) ----
  float S4[4], pmin[4];
#pragma unroll
  for (int r = 0; r < 4; ++r) {
    S4[r] = Ssh[mt * 16 + (lane >> 4) * 4 + r];
    pmin[r] = FLT_MAX;
  }
#pragma unroll
  for (int nt = 0; nt < 16; ++nt)
#pragma unroll
    for (int r = 0; r < 4; ++r) {
      float X = __fadd_rn(S4[r], __fmul_rn(-2.0f, acc[nt][r]));
      acc[nt][r] = X;
      pmin[r] = fminf(pmin[r], X);
    }
#pragma unroll
  for (int r = 0; r < 4; ++r)
#pragma unroll
    for (int off = 1; off < 16; off <<= 1)
      pmin[r] = fminf(pmin[r], __shfl_xor(pmin[r], off));
  if ((lane & 15) == 0) {
#pragma unroll
    for (int r = 0; r < 4; ++r)
      Wmin[wv][(lane >> 4) * 4 + r] = pmin[r];
  }
  __syncthreads();
  if (t < PXT) {
    int m2 = (t >> 4) * 2;
    Thr[t] = fminf(Wmin[m2][t & 15], Wmin[m2 + 1][t & 15]) + MARGIN;
  }
  __syncthreads();

  // ---- enqueue candidates ----
#pragma unroll
  for (int r = 0; r < 4; ++r) {
    int px = mt * 16 + (lane >> 4) * 4 + r;
    float th = Thr[px];
#pragma unroll
    for (int nt = 0; nt < 16; ++nt) {
      if (acc[nt][r] <= th) {
        int slot = atomicAdd(&qcnt[px], 1);
        if (slot < QCAP) qk[px][slot] = nh * 256 + nt * 16 + (lane & 15);
      }
    }
  }
  __syncthreads();

  // ---- exact np re-score (wave wv: px octet, slot = lane&7) ----
  {
    int px  = wv * 8 + (lane >> 3);
    int cnt = qcnt[px]; cnt = cnt < QCAP ? cnt : QCAP;
    float S = Ssh[px];
    float bv = FLT_MAX; int bk = 0x7fffffff;
#pragma unroll
    for (int m = 0; m < 2; ++m) {
      int slot = (lane & 7) + 8 * m;
      if (__any(slot < cnt)) {
        if (slot < cnt) {
          int k = qk[px][slot];
          float v = np_score(&Zs[px][0], w + ((size_t)c * NK + k) * ND, S);
          if (v < bv || (v == bv && k < bk)) { bv = v; bk = k; }
        }
      }
    }
#pragma unroll
    for (int off = 1; off < 8; off <<= 1) {
      float ov = __shfl_xor(bv, off);
      int   ok = __shfl_xor(bk, off);
      if (ov < bv || (ov == bv && ok < bk)) { bv = ov; bk = ok; }
    }
    if ((lane & 7) == 0) KB[px] = bk;
  }
  __syncthreads();

  // ---- gather + transpose-write both outputs (R5 numerics, coalesced) ----
  {
    int px = t & 63, dg = t >> 6;
    int kidx = KB[px];
    const float* er = w + ((size_t)c * NK + kidx) * ND;
    const size_t OUT2 = (size_t)NB * ND * NHW;
    size_t base = (size_t)b * ND * NHW + n0 + px;
#pragma unroll
    for (int j = 0; j < 32; ++j) {
      int d = dg * 32 + j;
      float q  = er[d];
      float zv = Zs[px][d];
      out[base + (size_t)d * NHW]        = __fadd_rn(zv, __fsub_rn(q, zv));
      out[base + (size_t)d * NHW + OUT2] = q;
    }
  }
}

extern "C" void kernel_launch(void* const* d_in, const int* in_sizes, int n_in,
                              void* d_out, int out_size, void* d_ws, size_t ws_size,
                              hipStream_t stream) {
  const float* z = (const float*)d_in[0];
  const int*   C = (const int*)d_in[1];
  const float* w = (const float*)d_in[2];
  float* out = (float*)d_out;

  const size_t NWEL = (size_t)NCOND * NK * ND;            // 2,097,152
  unsigned short* whi = (unsigned short*)d_ws;
  unsigned short* wlo = whi + NWEL;
  bool pre = ws_size >= NWEL * 2 * sizeof(unsigned short); // 8 MB

  if (pre) {
    k_split<<<(int)(NWEL / 1024), 256, 0, stream>>>(w, whi, wlo);
    k_mfma<1><<<NB * (NHW / PXT), 512, 0, stream>>>(z, C, w, whi, wlo, out);
  } else {
    k_mfma<0><<<NB * (NHW / PXT), 512, 0, stream>>>(z, C, w, whi, wlo, out);
  }
}

// Round 10
// 274.248 us; speedup vs baseline: 6.6072x; 1.1552x over previous
//
#include <hip/hip_runtime.h>
#include <cfloat>

#define NB    32
#define ND    256
#define NK    512
#define NCOND 16
#define NHW   4096
#define PXT   64
#define ZSTR  260          // floats; 1040B rows
#define ESTR  40           // ushorts; 80B rows
#define MARGIN 1.3e-4f     // validated R6-R9
#define QCAP  16

typedef __attribute__((ext_vector_type(8))) short bf16x8;
typedef __attribute__((ext_vector_type(4))) float f32x4;

// C declared int64 in the reference; detect storage width on device.
__device__ __forceinline__ int loadC(const int* __restrict__ C, int b) {
  int orodd = 0;
#pragma unroll
  for (int i = 1; i < 32; i += 2) orodd |= C[i];
  return (orodd == 0) ? C[2 * b] : C[b];
}

// Exact np-replica score for one (pixel,code) — verbatim op order from R5-R9.
__device__ float np_score(const float* __restrict__ zrow,
                          const float* __restrict__ er, float S) {
  float P0 = 0.f, P1 = 0.f, P2 = 0.f, P3 = 0.f;
  for (int ch = 0; ch < 16; ++ch) {
    const float* eb = er + ch * 16;
    float4 e0 = *(const float4*)(eb + 0);
    float4 e1 = *(const float4*)(eb + 4);
    float4 e2 = *(const float4*)(eb + 8);
    float4 e3 = *(const float4*)(eb + 12);
    const float* zb = zrow + ch * 16;
    float4 z0 = *(const float4*)(zb + 0);
    float4 z1 = *(const float4*)(zb + 4);
    float4 z2 = *(const float4*)(zb + 8);
    float4 z3 = *(const float4*)(zb + 12);
    P0 = __fadd_rn(P0, __fmul_rn(z3.x, e3.x));
    P0 = __fadd_rn(P0, __fmul_rn(z2.x, e2.x));
    P0 = __fadd_rn(P0, __fmul_rn(z1.x, e1.x));
    P0 = __fadd_rn(P0, __fmul_rn(z0.x, e0.x));
    P1 = __fadd_rn(P1, __fmul_rn(z3.y, e3.y));
    P1 = __fadd_rn(P1, __fmul_rn(z2.y, e2.y));
    P1 = __fadd_rn(P1, __fmul_rn(z1.y, e1.y));
    P1 = __fadd_rn(P1, __fmul_rn(z0.y, e0.y));
    P2 = __fadd_rn(P2, __fmul_rn(z3.z, e3.z));
    P2 = __fadd_rn(P2, __fmul_rn(z2.z, e2.z));
    P2 = __fadd_rn(P2, __fmul_rn(z1.z, e1.z));
    P2 = __fadd_rn(P2, __fmul_rn(z0.z, e0.z));
    P3 = __fadd_rn(P3, __fmul_rn(z3.w, e3.w));
    P3 = __fadd_rn(P3, __fmul_rn(z2.w, e2.w));
    P3 = __fadd_rn(P3, __fmul_rn(z1.w, e1.w));
    P3 = __fadd_rn(P3, __fmul_rn(z0.w, e0.w));
  }
  float G = __fadd_rn(__fadd_rn(P0, P1), __fadd_rn(P2, P3));
  return __fadd_rn(S, __fmul_rn(-2.0f, G));
}

// round-to-nearest-even fp32 -> bf16 (bit trick, finite inputs)
__device__ __forceinline__ unsigned short rne_bf16(float x) {
  unsigned u = __float_as_uint(x);
  u += 0x7fffu + ((u >> 16) & 1u);
  return (unsigned short)(u >> 16);
}

// pre-kernel: split codebook into bf16 hi/lo, K-MAJOR layout:
// dst[cond][ks][code][32] with ks = d/32, kk = d%32  (coalesced per-ks staging)
__global__ __launch_bounds__(256) void k_split(
    const float* __restrict__ w, unsigned short* __restrict__ whi,
    unsigned short* __restrict__ wlo) {
  int i = (blockIdx.x * 256 + threadIdx.x) * 4;   // src elem (4 per thread)
  float4 v = *(const float4*)&w[i];
  int ci   = i >> 17;            // /131072
  int rem  = i & 131071;
  int code = rem >> 8;
  int d    = rem & 255;
  int dst  = (ci << 17) + ((d >> 5) << 14) + (code << 5) + (d & 31);
  ushort4 h, l;
  float hf;
  h.x = rne_bf16(v.x); hf = __uint_as_float((unsigned)h.x << 16); l.x = rne_bf16(v.x - hf);
  h.y = rne_bf16(v.y); hf = __uint_as_float((unsigned)h.y << 16); l.y = rne_bf16(v.y - hf);
  h.z = rne_bf16(v.z); hf = __uint_as_float((unsigned)h.z << 16); l.z = rne_bf16(v.z - hf);
  h.w = rne_bf16(v.w); hf = __uint_as_float((unsigned)h.w << 16); l.w = rne_bf16(v.w - hf);
  *(ushort4*)&whi[dst] = h;
  *(ushort4*)&wlo[dst] = l;
}

template <int PRE>
__global__ __launch_bounds__(512, 2) void k_mfma(
    const float* __restrict__ z, const int* __restrict__ Cc,
    const float* __restrict__ w,
    const unsigned short* __restrict__ whi,
    const unsigned short* __restrict__ wlo,
    float* __restrict__ out) {
  __shared__ __align__(16) float Zs[PXT][ZSTR];            // 66.6 KB
  __shared__ __align__(16) unsigned short EsH[NK][ESTR];   // 40 KB
  __shared__ __align__(16) unsigned short EsL[NK][ESTR];   // 40 KB
  __shared__ float Ssh[PXT];
  __shared__ float Wmin[8][32];
  __shared__ float Thr[PXT];
  __shared__ int   qcnt[PXT], KB[PXT];
  __shared__ int   qk[PXT][QCAP];

  // XCD-aware bijective swizzle (nwg = 2048 = 8*256)
  int orig = blockIdx.x;
  int blk  = (orig & 7) * 256 + (orig >> 3);
  int b    = blk >> 6;
  int n0   = (blk & 63) * PXT;
  int c    = loadC(Cc, b);
  int t    = threadIdx.x;         // 0..511
  int lane = t & 63;
  int wv   = t >> 6;              // 0..7
  int mw   = wv >> 2;             // 0..1: px half (32 px)
  int nw   = wv & 3;              // 0..3: code quarter (128 codes)

  // ---- phase 0: stage z tile [64 px][256 d] (coalesced) ----
  {
    int px = t & 63, dg = t >> 6;
    const float* zp = z + (size_t)b * ND * NHW + n0 + px;
#pragma unroll
    for (int j = 0; j < 32; ++j) {
      int d = dg * 32 + j;
      Zs[px][d] = zp[(size_t)d * NHW];
    }
  }
  if (t < PXT) qcnt[t] = 0;
  __syncthreads();

  // ---- S[px]: np pairwise replica, parallel (8 lanes per px own np's 8 accs) ----
  {
    int px = t >> 3, j = t & 7;
    float r0 = 0.f, r1 = 0.f;
#pragma unroll
    for (int i = 0; i < 16; ++i) {
      float v0 = Zs[px][8 * i + j];
      float v1 = Zs[px][128 + 8 * i + j];
      r0 = __fadd_rn(r0, __fmul_rn(v0, v0));
      r1 = __fadd_rn(r1, __fmul_rn(v1, v1));
    }
    // exact np tree: ((r0+r1)+(r2+r3))+((r4+r5)+(r6+r7)) per 128-block
#pragma unroll
    for (int off = 1; off < 8; off <<= 1) {
      r0 = __fadd_rn(r0, __shfl_xor(r0, off));
      r1 = __fadd_rn(r1, __shfl_xor(r1, off));
    }
    if (j == 0) Ssh[px] = __fadd_rn(r0, r1);
  }

  // ---- staging prefetch: k-major flat copy (PRE) / row-owner (fallback) ----
  bf16x8 pv[8];     // PRE: 4 hi + 4 lo 16B chunks
  float4 pf[8];     // !PRE
  const size_t cb  = (size_t)c << 17;            // c * 131072
  size_t wrow = ((size_t)c * NK + t) * ND;       // !PRE: thread owns row t

  auto issue = [&](int ks) {
    if constexpr (PRE) {
      const unsigned short* hk = whi + cb + ((size_t)ks << 14) + t * 8;
      const unsigned short* lk = wlo + cb + ((size_t)ks << 14) + t * 8;
#pragma unroll
      for (int p = 0; p < 4; ++p) {
        pv[p]     = *(const bf16x8*)(hk + p * 4096);
        pv[4 + p] = *(const bf16x8*)(lk + p * 4096);
      }
    } else {
      const float* fr = w + wrow + ks * 32;
#pragma unroll
      for (int j = 0; j < 8; ++j) pf[j] = *(const float4*)(fr + j * 4);
    }
  };
  issue(0);

  f32x4 acc[2][8];
#pragma unroll
  for (int fr = 0; fr < 2; ++fr)
#pragma unroll
    for (int nt = 0; nt < 8; ++nt) acc[fr][nt] = (f32x4){0.f, 0.f, 0.f, 0.f};

  int ar0  = mw * 32 + (lane & 15);   // A rows (z) for fr=0 / fr=1
  int koff = (lane >> 4) * 8;         // k-element offset within ks slice
  int cbase = nw * 128 + (lane & 15); // B row (code) base

#pragma unroll 1
  for (int ks = 0; ks < 8; ++ks) {
    __syncthreads();                  // Es of previous step fully consumed
    if constexpr (PRE) {
      int code = (t >> 2);            // + p*128 per pass
      int kk   = (t & 3) * 8;
#pragma unroll
      for (int p = 0; p < 4; ++p) {
        *(bf16x8*)&EsH[p * 128 + code][kk] = pv[p];
        *(bf16x8*)&EsL[p * 128 + code][kk] = pv[4 + p];
      }
    } else {
#pragma unroll
      for (int j = 0; j < 4; ++j) {
        float xs[8] = {pf[2 * j].x, pf[2 * j].y, pf[2 * j].z, pf[2 * j].w,
                       pf[2 * j + 1].x, pf[2 * j + 1].y, pf[2 * j + 1].z, pf[2 * j + 1].w};
        bf16x8 h, l;
#pragma unroll
        for (int q = 0; q < 8; ++q) {
          unsigned short hb = rne_bf16(xs[q]);
          float hf = __uint_as_float((unsigned)hb << 16);
          h[q] = (short)hb;
          l[q] = (short)rne_bf16(xs[q] - hf);
        }
        *(bf16x8*)&EsH[t][j * 8] = h;
        *(bf16x8*)&EsL[t][j * 8] = l;
      }
    }
    if (ks < 7) issue(ks + 1);        // latency hides under MFMA phase
    __syncthreads();                  // Es ready

    // rebuild A-frags (z hi/lo) for this ks from fp32 Zs
    bf16x8 ah[2], al[2];
#pragma unroll
    for (int fr = 0; fr < 2; ++fr) {
      const float* zr = &Zs[ar0 + fr * 16][ks * 32 + koff];
      float4 za = *(const float4*)zr;
      float4 zb = *(const float4*)(zr + 4);
      float xs[8] = {za.x, za.y, za.z, za.w, zb.x, zb.y, zb.z, zb.w};
      bf16x8 h, l;
#pragma unroll
      for (int j = 0; j < 8; ++j) {
        unsigned short hb = rne_bf16(xs[j]);
        float hf = __uint_as_float((unsigned)hb << 16);
        h[j] = (short)hb;
        l[j] = (short)rne_bf16(xs[j] - hf);
      }
      ah[fr] = h; al[fr] = l;
    }

#pragma unroll
    for (int nt = 0; nt < 8; ++nt) {
      const bf16x8 bh = *(const bf16x8*)&EsH[cbase + nt * 16][koff];
      const bf16x8 bl = *(const bf16x8*)&EsL[cbase + nt * 16][koff];
#pragma unroll
      for (int fr = 0; fr < 2; ++fr) {
        acc[fr][nt] = __builtin_amdgcn_mfma_f32_16x16x32_bf16(ah[fr], bh, acc[fr][nt], 0, 0, 0);
        acc[fr][nt] = __builtin_amdgcn_mfma_f32_16x16x32_bf16(al[fr], bh, acc[fr][nt], 0, 0, 0);
        acc[fr][nt] = __builtin_amdgcn_mfma_f32_16x16x32_bf16(ah[fr], bl, acc[fr][nt], 0, 0, 0);
      }
    }
  }

  // ---- X = fl(S + fl(-2G)); per-px min over this wave's 128 codes ----
  float pmin[2][4], S4[2][4];
#pragma unroll
  for (int fr = 0; fr < 2; ++fr)
#pragma unroll
    for (int r = 0; r < 4; ++r) {
      S4[fr][r] = Ssh[mw * 32 + fr * 16 + (lane >> 4) * 4 + r];
      pmin[fr][r] = FLT_MAX;
    }
#pragma unroll
  for (int fr = 0; fr < 2; ++fr)
#pragma unroll
    for (int nt = 0; nt < 8; ++nt)
#pragma unroll
      for (int r = 0; r < 4; ++r) {
        float X = __fadd_rn(S4[fr][r], __fmul_rn(-2.0f, acc[fr][nt][r]));
        acc[fr][nt][r] = X;
        pmin[fr][r] = fminf(pmin[fr][r], X);
      }
#pragma unroll
  for (int fr = 0; fr < 2; ++fr)
#pragma unroll
    for (int r = 0; r < 4; ++r)
#pragma unroll
      for (int off = 1; off < 16; off <<= 1)
        pmin[fr][r] = fminf(pmin[fr][r], __shfl_xor(pmin[fr][r], off));
  if ((lane & 15) == 0) {
#pragma unroll
    for (int fr = 0; fr < 2; ++fr)
#pragma unroll
      for (int r = 0; r < 4; ++r)
        Wmin[wv][fr * 16 + (lane >> 4) * 4 + r] = pmin[fr][r];
  }
  __syncthreads();
  if (t < PXT) {
    int m2 = (t >> 5) * 4, i = t & 31;
    Thr[t] = fminf(fminf(Wmin[m2][i], Wmin[m2 + 1][i]),
                   fminf(Wmin[m2 + 2][i], Wmin[m2 + 3][i])) + MARGIN;
  }
  __syncthreads();

  // ---- enqueue candidates ----
#pragma unroll
  for (int fr = 0; fr < 2; ++fr)
#pragma unroll
    for (int r = 0; r < 4; ++r) {
      int px = mw * 32 + fr * 16 + (lane >> 4) * 4 + r;
      float th = Thr[px];
#pragma unroll
      for (int nt = 0; nt < 8; ++nt) {
        if (acc[fr][nt][r] <= th) {
          int slot = atomicAdd(&qcnt[px], 1);
          if (slot < QCAP) qk[px][slot] = nw * 128 + nt * 16 + (lane & 15);
        }
      }
    }
  __syncthreads();

  // ---- exact np re-score (wave wv: px octet, slot = lane&7) ----
  {
    int px  = wv * 8 + (lane >> 3);
    int cnt = qcnt[px]; cnt = cnt < QCAP ? cnt : QCAP;
    float S = Ssh[px];
    float bv = FLT_MAX; int bk = 0x7fffffff;
#pragma unroll
    for (int m = 0; m < 2; ++m) {
      int slot = (lane & 7) + 8 * m;
      if (__any(slot < cnt)) {
        if (slot < cnt) {
          int k = qk[px][slot];
          float v = np_score(&Zs[px][0], w + ((size_t)c * NK + k) * ND, S);
          if (v < bv || (v == bv && k < bk)) { bv = v; bk = k; }
        }
      }
    }
#pragma unroll
    for (int off = 1; off < 8; off <<= 1) {
      float ov = __shfl_xor(bv, off);
      int   ok = __shfl_xor(bk, off);
      if (ov < bv || (ov == bv && ok < bk)) { bv = ov; bk = ok; }
    }
    if ((lane & 7) == 0) KB[px] = bk;
  }
  __syncthreads();

  // ---- gather + transpose-write both outputs (R5 numerics) ----
  {
    int px = t & 63, dg = t >> 6;
    int kidx = KB[px];
    const float* er = w + ((size_t)c * NK + kidx) * ND;
    const size_t OUT2 = (size_t)NB * ND * NHW;
    size_t base = (size_t)b * ND * NHW + n0 + px;
#pragma unroll
    for (int j = 0; j < 32; ++j) {
      int d = dg * 32 + j;
      float q  = er[d];
      float zv = Zs[px][d];
      out[base + (size_t)d * NHW]        = __fadd_rn(zv, __fsub_rn(q, zv));
      out[base + (size_t)d * NHW + OUT2] = q;
    }
  }
}

extern "C" void kernel_launch(void* const* d_in, const int* in_sizes, int n_in,
                              void* d_out, int out_size, void* d_ws, size_t ws_size,
                              hipStream_t stream) {
  const float* z = (const float*)d_in[0];
  const int*   C = (const int*)d_in[1];
  const float* w = (const float*)d_in[2];
  float* out = (float*)d_out;

  const size_t NWEL = (size_t)NCOND * NK * ND;            // 2,097,152
  unsigned short* whi = (unsigned short*)d_ws;
  unsigned short* wlo = whi + NWEL;
  bool pre = ws_size >= NWEL * 2 * sizeof(unsigned short); // 8 MB

  if (pre) {
    k_split<<<(int)(NWEL / 1024), 256, 0, stream>>>(w, whi, wlo);
    k_mfma<1><<<NB * (NHW / PXT), 512, 0, stream>>>(z, C, w, whi, wlo, out);
  } else {
    k_mfma<0><<<NB * (NHW / PXT), 512, 0, stream>>>(z, C, w, whi, wlo, out);
  }
}

// Round 11
// 243.602 us; speedup vs baseline: 7.4384x; 1.1258x over previous
//
#include <hip/hip_runtime.h>
#include <cfloat>

#define NB    32
#define ND    256
#define NK    512
#define NCOND 16
#define NHW   4096
#define PXT   64
#define MARGIN 1.3e-4f   // validated R6-R10; 2-product fast err 2*delta ~ 8.6e-5 < MARGIN
#define QCAP  16

typedef __attribute__((ext_vector_type(8))) short bf16x8;
typedef __attribute__((ext_vector_type(4))) float f32x4;

// C declared int64 in the reference; detect storage width on device.
__device__ __forceinline__ int loadC(const int* __restrict__ C, int b) {
  int orodd = 0;
#pragma unroll
  for (int i = 1; i < 32; i += 2) orodd |= C[i];
  return (orodd == 0) ? C[2 * b] : C[b];
}

// round-to-nearest-even fp32 -> bf16 (bit trick, finite inputs)
__device__ __forceinline__ unsigned short rne_bf16(float x) {
  unsigned u = __float_as_uint(x);
  u += 0x7fffu + ((u >> 16) & 1u);
  return (unsigned short)(u >> 16);
}

// async global->LDS, 16B per lane, LDS dest = uniform base + lane*16
__device__ __forceinline__ void gl2lds16(const void* g, void* l) {
  __builtin_amdgcn_global_load_lds(
      (const __attribute__((address_space(1))) void*)g,
      (__attribute__((address_space(3))) void*)l, 16, 0, 0);
}

// Exact np-replica score, z gathered from original [b][d][n] layout.
// FP op order verbatim from the passing R5-R10 kernels (loads reordered only).
__device__ float np_score_g(const float* __restrict__ z, size_t zoff,
                            const float* __restrict__ er, float S) {
  float P0 = 0.f, P1 = 0.f, P2 = 0.f, P3 = 0.f;
  for (int ch = 0; ch < 16; ++ch) {
    const float* eb = er + ch * 16;
    float4 e0 = *(const float4*)(eb + 0);
    float4 e1 = *(const float4*)(eb + 4);
    float4 e2 = *(const float4*)(eb + 8);
    float4 e3 = *(const float4*)(eb + 12);
    float zb[16];
#pragma unroll
    for (int q = 0; q < 16; ++q)
      zb[q] = z[zoff + (size_t)(ch * 16 + q) * NHW];
    P0 = __fadd_rn(P0, __fmul_rn(zb[12], e3.x));
    P0 = __fadd_rn(P0, __fmul_rn(zb[8],  e2.x));
    P0 = __fadd_rn(P0, __fmul_rn(zb[4],  e1.x));
    P0 = __fadd_rn(P0, __fmul_rn(zb[0],  e0.x));
    P1 = __fadd_rn(P1, __fmul_rn(zb[13], e3.y));
    P1 = __fadd_rn(P1, __fmul_rn(zb[9],  e2.y));
    P1 = __fadd_rn(P1, __fmul_rn(zb[5],  e1.y));
    P1 = __fadd_rn(P1, __fmul_rn(zb[1],  e0.y));
    P2 = __fadd_rn(P2, __fmul_rn(zb[14], e3.z));
    P2 = __fadd_rn(P2, __fmul_rn(zb[10], e2.z));
    P2 = __fadd_rn(P2, __fmul_rn(zb[6],  e1.z));
    P2 = __fadd_rn(P2, __fmul_rn(zb[2],  e0.z));
    P3 = __fadd_rn(P3, __fmul_rn(zb[15], e3.w));
    P3 = __fadd_rn(P3, __fmul_rn(zb[11], e2.w));
    P3 = __fadd_rn(P3, __fmul_rn(zb[7],  e1.w));
    P3 = __fadd_rn(P3, __fmul_rn(zb[3],  e0.w));
  }
  float G = __fadd_rn(__fadd_rn(P0, P1), __fadd_rn(P2, P3));
  return __fadd_rn(S, __fmul_rn(-2.0f, G));
}

// pre-kernel: codebook bf16-hi (RNE), k-major: whi[cond][ks=d/32][code][d%32]
__global__ __launch_bounds__(256) void k_split(
    const float* __restrict__ w, unsigned short* __restrict__ whi) {
  int i = (blockIdx.x * 256 + threadIdx.x) * 4;
  float4 v = *(const float4*)&w[i];
  int ci = i >> 17, rem = i & 131071;
  int code = rem >> 8, d = rem & 255;
  int dst = (ci << 17) + ((d >> 5) << 14) + (code << 5) + (d & 31);
  ushort4 h;
  h.x = rne_bf16(v.x); h.y = rne_bf16(v.y);
  h.z = rne_bf16(v.z); h.w = rne_bf16(v.w);
  *(ushort4*)&whi[dst] = h;
}

template <int PRE>
__global__ __launch_bounds__(512, 4) void k_vq(
    const float* __restrict__ z, const int* __restrict__ Cc,
    const float* __restrict__ w, const unsigned short* __restrict__ whi,
    float* __restrict__ out) {
  // Es chunk layout: chunk(code, phys) at ushort code*32 + phys*8,
  // phys = q_logical ^ ((code>>1)&3)  -> 2-way banks on read AND write (free)
  __shared__ __align__(16) unsigned short EsH[NK * 32];   // 32 KB
  __shared__ float Ssh[PXT];
  __shared__ float Wmin[8][32];
  __shared__ float Thr[PXT];
  __shared__ int   qcnt[PXT], KB[PXT];
  __shared__ int   qk[PXT][QCAP];

  // XCD-aware bijective swizzle (nwg = 2048 = 8*256)
  int orig = blockIdx.x;
  int blk  = (orig & 7) * 256 + (orig >> 3);
  int b    = blk >> 6;
  int n0   = (blk & 63) * PXT;
  int c    = loadC(Cc, b);
  int t    = threadIdx.x;
  int lane = t & 63;
  int wv   = t >> 6;            // 0..7
  int mw   = wv >> 2;           // px half (32 px)
  int nw   = wv & 3;            // code quarter (128 codes)

  if (t < PXT) qcnt[t] = 0;

  const size_t zab = (size_t)b * ND * NHW;
  const size_t cbu = (size_t)c * (NK * ND);    // whi ushort base
  const int ar_n = n0 + mw * 32 + (lane & 15); // A rows: n, n+16
  const int koff = (lane >> 4) * 8;

  f32x4 acc0[8], acc1[8];
#pragma unroll
  for (int nt = 0; nt < 8; ++nt) {
    acc0[nt] = (f32x4){0.f, 0.f, 0.f, 0.f};
    acc1[nt] = (f32x4){0.f, 0.f, 0.f, 0.f};
  }

  float zf0[8], zf1[8];
  const float* zA = z + zab + ar_n;

#pragma unroll 1
  for (int ks = 0; ks < 8; ++ks) {
    __syncthreads();                       // Es[ks-1] fully consumed
    if constexpr (PRE) {
      // stage 32 KB: linear LDS dest, inverse-swizzled global src (m173)
#pragma unroll
      for (int p = 0; p < 4; ++p) {
        int code = p * 128 + wv * 16 + (lane >> 2);
        int ql   = (lane & 3) ^ ((code >> 1) & 3);
        const unsigned short* src = whi + cbu + ks * (NK * 32) + code * 32 + ql * 8;
        gl2lds16(src, &EsH[(p * 512 + wv * 64) * 8]);
      }
    } else {
#pragma unroll
      for (int p = 0; p < 4; ++p) {
        int code = p * 128 + (t >> 2);
        int ql   = t & 3;
        const float* sf = w + ((size_t)c * NK + code) * ND + ks * 32 + ql * 8;
        float4 f0 = *(const float4*)sf;
        float4 f1 = *(const float4*)(sf + 4);
        float xs[8] = {f0.x, f0.y, f0.z, f0.w, f1.x, f1.y, f1.z, f1.w};
        bf16x8 h;
#pragma unroll
        for (int q = 0; q < 8; ++q) h[q] = (short)rne_bf16(xs[q]);
        int phys = ql ^ ((code >> 1) & 3);
        *(bf16x8*)&EsH[code * 32 + phys * 8] = h;
      }
    }
    // A-operand z loads for this ks (drained by the same barrier)
#pragma unroll
    for (int j = 0; j < 8; ++j) {
      size_t doff = (size_t)(ks * 32 + koff + j) * NHW;
      zf0[j] = zA[doff];
      zf1[j] = zA[doff + 16];
    }
    __syncthreads();                       // vmcnt(0): Es + zf ready

    // build A hi/lo: hi = truncate-to-bf16 (exact residual), lo = RNE(z-hi)
    bf16x8 ah0, al0, ah1, al1;
#pragma unroll
    for (int j = 0; j < 8; ++j) {
      unsigned u0 = __float_as_uint(zf0[j]) & 0xffff0000u;
      ah0[j] = (short)(u0 >> 16);
      al0[j] = (short)rne_bf16(zf0[j] - __uint_as_float(u0));
      unsigned u1 = __float_as_uint(zf1[j]) & 0xffff0000u;
      ah1[j] = (short)(u1 >> 16);
      al1[j] = (short)rne_bf16(zf1[j] - __uint_as_float(u1));
    }
#pragma unroll
    for (int nt = 0; nt < 8; ++nt) {
      int code = nw * 128 + nt * 16 + (lane & 15);
      int phys = (lane >> 4) ^ ((code >> 1) & 3);
      bf16x8 bh = *(const bf16x8*)&EsH[code * 32 + phys * 8];
      acc0[nt] = __builtin_amdgcn_mfma_f32_16x16x32_bf16(ah0, bh, acc0[nt], 0, 0, 0);
      acc0[nt] = __builtin_amdgcn_mfma_f32_16x16x32_bf16(al0, bh, acc0[nt], 0, 0, 0);
      acc1[nt] = __builtin_amdgcn_mfma_f32_16x16x32_bf16(ah1, bh, acc1[nt], 0, 0, 0);
      acc1[nt] = __builtin_amdgcn_mfma_f32_16x16x32_bf16(al1, bh, acc1[nt], 0, 0, 0);
    }
  }

  // ---- S[px]: np pairwise replica from global z (L2-hot lines) ----
  {
    int spx = t >> 3, sj = t & 7;
    size_t sb = zab + n0 + spx;
    float r0 = 0.f, r1 = 0.f;
#pragma unroll
    for (int i = 0; i < 16; ++i) {
      float v0 = z[sb + (size_t)(8 * i + sj) * NHW];
      float v1 = z[sb + (size_t)(128 + 8 * i + sj) * NHW];
      r0 = __fadd_rn(r0, __fmul_rn(v0, v0));
      r1 = __fadd_rn(r1, __fmul_rn(v1, v1));
    }
#pragma unroll
    for (int off = 1; off < 8; off <<= 1) {
      r0 = __fadd_rn(r0, __shfl_xor(r0, off));
      r1 = __fadd_rn(r1, __shfl_xor(r1, off));
    }
    if (sj == 0) Ssh[spx] = __fadd_rn(r0, r1);
  }
  __syncthreads();

  // ---- X = fl(S + fl(-2G)); per-px min over this wave's 128 codes ----
  float pmin0[4], pmin1[4], S40[4], S41[4];
#pragma unroll
  for (int r = 0; r < 4; ++r) {
    int pr = mw * 32 + (lane >> 4) * 4 + r;
    S40[r] = Ssh[pr];
    S41[r] = Ssh[pr + 16];
    pmin0[r] = FLT_MAX; pmin1[r] = FLT_MAX;
  }
#pragma unroll
  for (int nt = 0; nt < 8; ++nt)
#pragma unroll
    for (int r = 0; r < 4; ++r) {
      float X0 = __fadd_rn(S40[r], __fmul_rn(-2.0f, acc0[nt][r]));
      float X1 = __fadd_rn(S41[r], __fmul_rn(-2.0f, acc1[nt][r]));
      acc0[nt][r] = X0; acc1[nt][r] = X1;
      pmin0[r] = fminf(pmin0[r], X0);
      pmin1[r] = fminf(pmin1[r], X1);
    }
#pragma unroll
  for (int r = 0; r < 4; ++r)
#pragma unroll
    for (int off = 1; off < 16; off <<= 1) {
      pmin0[r] = fminf(pmin0[r], __shfl_xor(pmin0[r], off));
      pmin1[r] = fminf(pmin1[r], __shfl_xor(pmin1[r], off));
    }
  if ((lane & 15) == 0) {
#pragma unroll
    for (int r = 0; r < 4; ++r) {
      Wmin[wv][(lane >> 4) * 4 + r]      = pmin0[r];
      Wmin[wv][16 + (lane >> 4) * 4 + r] = pmin1[r];
    }
  }
  __syncthreads();
  if (t < PXT) {
    int m2 = (t >> 5) * 4, i = t & 31;
    Thr[t] = fminf(fminf(Wmin[m2][i], Wmin[m2 + 1][i]),
                   fminf(Wmin[m2 + 2][i], Wmin[m2 + 3][i])) + MARGIN;
  }
  __syncthreads();

  // ---- enqueue candidates ----
#pragma unroll
  for (int r = 0; r < 4; ++r) {
    int px0 = mw * 32 + (lane >> 4) * 4 + r;
    float th0 = Thr[px0], th1 = Thr[px0 + 16];
#pragma unroll
    for (int nt = 0; nt < 8; ++nt) {
      int kcode = nw * 128 + nt * 16 + (lane & 15);
      if (acc0[nt][r] <= th0) {
        int slot = atomicAdd(&qcnt[px0], 1);
        if (slot < QCAP) qk[px0][slot] = kcode;
      }
      if (acc1[nt][r] <= th1) {
        int slot = atomicAdd(&qcnt[px0 + 16], 1);
        if (slot < QCAP) qk[px0 + 16][slot] = kcode;
      }
    }
  }
  __syncthreads();

  // ---- exact np re-score (wave wv: px octet, slot = lane&7) ----
  {
    int px  = wv * 8 + (lane >> 3);
    int cnt = qcnt[px]; cnt = cnt < QCAP ? cnt : QCAP;
    float S = Ssh[px];
    size_t zoff = zab + n0 + px;
    float bv = FLT_MAX; int bk = 0x7fffffff;
#pragma unroll
    for (int m = 0; m < 2; ++m) {
      int slot = (lane & 7) + 8 * m;
      if (__any(slot < cnt)) {
        if (slot < cnt) {
          int k = qk[px][slot];
          float v = np_score_g(z, zoff, w + ((size_t)c * NK + k) * ND, S);
          if (v < bv || (v == bv && k < bk)) { bv = v; bk = k; }
        }
      }
    }
#pragma unroll
    for (int off = 1; off < 8; off <<= 1) {
      float ov = __shfl_xor(bv, off);
      int   ok = __shfl_xor(bk, off);
      if (ov < bv || (ov == bv && ok < bk)) { bv = ov; bk = ok; }
    }
    if ((lane & 7) == 0) KB[px] = bk;
  }
  __syncthreads();

  // ---- gather + transpose-write both outputs (z re-read, L2-hot) ----
  {
    int px = t & 63, dg = t >> 6;
    int kidx = KB[px];
    const float* er = w + ((size_t)c * NK + kidx) * ND;
    const size_t OUT2 = (size_t)NB * ND * NHW;
    size_t base = zab + n0 + px;
#pragma unroll
    for (int j = 0; j < 32; ++j) {
      int d = dg * 32 + j;
      float q  = er[d];
      float zv = z[base + (size_t)d * NHW];
      out[base + (size_t)d * NHW]        = __fadd_rn(zv, __fsub_rn(q, zv));
      out[base + (size_t)d * NHW + OUT2] = q;
    }
  }
}

extern "C" void kernel_launch(void* const* d_in, const int* in_sizes, int n_in,
                              void* d_out, int out_size, void* d_ws, size_t ws_size,
                              hipStream_t stream) {
  const float* z = (const float*)d_in[0];
  const int*   C = (const int*)d_in[1];
  const float* w = (const float*)d_in[2];
  float* out = (float*)d_out;

  const size_t NWEL = (size_t)NCOND * NK * ND;   // 2,097,152
  unsigned short* whi = (unsigned short*)d_ws;
  bool pre = ws_size >= NWEL * sizeof(unsigned short);  // 4 MB

  if (pre) {
    k_split<<<(int)(NWEL / 1024), 256, 0, stream>>>(w, whi);
    k_vq<1><<<NB * (NHW / PXT), 512, 0, stream>>>(z, C, w, whi, out);
  } else {
    k_vq<0><<<NB * (NHW / PXT), 512, 0, stream>>>(z, C, w, whi, out);
  }
}